// Round 1
// baseline (23379.845 us; speedup 1.0000x reference)
//
#include <hip/hip_runtime.h>
#include <math.h>

#define B_    32768
#define T_    128
#define EMD_  128
#define CELL_ 128
#define OUT_  5
#define EPS_  1e-5f

// ---- workspace layout (in floats) ----
// wT:     [128][1024]  transposed weights: [k][g], g<512 -> w_ih[g][k], g>=512 -> w_hh[g-512][k]
// istats: [128][5]     per-t input moments: S0, S1, S00, S11, S01   (atomically accumulated)
// A0/A1/C:[128][128]   folded embed+BN coefficients: e = relu(x0*A0 + x1*A1 + C)
// zstats: [128][5][2]  per-(t,o) sum / sumsq of raw z               (atomically accumulated)
#define WS_WT     0
#define WS_ISTATS (128 * 1024)
#define WS_A0     (WS_ISTATS + 1024)
#define WS_A1     (WS_A0 + 128 * 128)
#define WS_C      (WS_A1 + 128 * 128)
#define WS_ZST    (WS_C + 128 * 128)

__device__ __forceinline__ float sigmoidf_(float x) {
  return 1.f / (1.f + __expf(-x));
}
__device__ __forceinline__ float tanhf_(float x) {
  // 1 - 2/(e^{2x}+1): correct saturation at +/-inf
  return 1.f - 2.f / (__expf(2.f * x) + 1.f);
}

// ---- kernel 1: per-timestep input moments ----
// grid 512 x 256: block handles 64 consecutive samples, thread = (t = tid>>1, i = tid&1)
__global__ void k_istats(const float* __restrict__ x, float* __restrict__ istats) {
  const int tid = threadIdx.x;
  const int t = tid >> 1;
  const int i = tid & 1;
  const long b0 = (long)blockIdx.x * 64;
  float s_v = 0.f, s_vv = 0.f, s_cross = 0.f;
  for (int s = 0; s < 64; ++s) {
    float v = x[(b0 + s) * 256 + tid];     // x[b][t][i], coalesced across tid
    float p = __shfl_xor(v, 1);            // partner component
    s_v += v;
    s_vv += v * v;
    s_cross += v * p;                      // only kept for i==0
  }
  float* st = istats + t * 5;
  if (i == 0) {
    atomicAdd(st + 0, s_v);
    atomicAdd(st + 2, s_vv);
    atomicAdd(st + 4, s_cross);
  } else {
    atomicAdd(st + 1, s_v);
    atomicAdd(st + 3, s_vv);
  }
}

// ---- kernel 2: transpose/pack gate weights: wT[k][g] ----
__global__ void k_prep_w(const float* __restrict__ w_ih, const float* __restrict__ w_hh,
                         float* __restrict__ wT) {
  int idx = blockIdx.x * 256 + threadIdx.x;   // 0 .. 131071
  int k = idx >> 10;
  int g = idx & 1023;
  wT[idx] = (g < 512) ? w_ih[g * 128 + k] : w_hh[(g - 512) * 128 + k];
}

// ---- kernel 3: fold embed linear + BN into per-(t,f) affine coefficients ----
__global__ void k_coef(const float* __restrict__ istats, const float* __restrict__ w_emb,
                       const float* __restrict__ b_emb, const float* __restrict__ gamma1,
                       const float* __restrict__ beta1, float* __restrict__ A0,
                       float* __restrict__ A1, float* __restrict__ C) {
  int idx = blockIdx.x * 256 + threadIdx.x;   // 0 .. 16383
  int t = idx >> 7, f = idx & 127;
  const float* st = istats + t * 5;
  const float invB = 1.f / (float)B_;
  float m0 = st[0] * invB, m1 = st[1] * invB;
  float v00 = st[2] * invB - m0 * m0;
  float v11 = st[3] * invB - m1 * m1;
  float c01 = st[4] * invB - m0 * m1;
  float w0 = w_emb[f * 2 + 0], w1 = w_emb[f * 2 + 1];
  float mu = m0 * w0 + m1 * w1 + b_emb[f];
  float var = w0 * w0 * v00 + w1 * w1 * v11 + 2.f * w0 * w1 * c01;
  float alpha = gamma1[f] * rsqrtf(var + EPS_);
  A0[t * 128 + f] = alpha * w0;
  A1[t * 128 + f] = alpha * w1;
  C[t * 128 + f] = alpha * (b_emb[f] - mu) + beta1[f];
}

// ---- kernel 4: the recurrent LSTM ----
// grid 1024 x 256: block owns 32 samples for all 128 timesteps.
// thread = (j = tid&127 -> cell index, sbg = tid>>7 -> half of the samples)
// Per timestep each thread computes the 4 gates of cell j for 16 samples.
// LDS eh[sb][k][{e,h}] is read as a wave-uniform broadcast in the gate loop.
__global__ __launch_bounds__(256, 2) void k_lstm(
    const float* __restrict__ x, const float* __restrict__ wT, const float* __restrict__ A0,
    const float* __restrict__ A1, const float* __restrict__ C, const float* __restrict__ b_ih,
    const float* __restrict__ b_hh, const float* __restrict__ w_out,
    const float* __restrict__ b_out, float* __restrict__ out, float* __restrict__ zstats) {
  __shared__ float eh[32][128][2];  // 32 KB: [sample][feature][{e,h}]
  __shared__ float xs[32][2];
  __shared__ float zs[32][5];

  const int tid = threadIdx.x;
  const int j = tid & 127;
  const int sbg = tid >> 7;
  const long b0 = (long)blockIdx.x * 32;

  const float bi = b_ih[j] + b_hh[j];
  const float bf = b_ih[128 + j] + b_hh[128 + j];
  const float bg = b_ih[256 + j] + b_hh[256 + j];
  const float bo = b_ih[384 + j] + b_hh[384 + j];

  float c[16];
#pragma unroll
  for (int s = 0; s < 16; ++s) c[s] = 0.f;
#pragma unroll
  for (int s = 0; s < 16; ++s) eh[sbg * 16 + s][j][1] = 0.f;  // h0 = 0

  const int zsb = tid / 5, zo = tid - zsb * 5;  // z roles for tid < 160

  for (int t = 0; t < T_; ++t) {
    __syncthreads();  // previous iteration's readers done; h-init visible at t=0
    if (tid < 64) {
      xs[tid >> 1][tid & 1] = x[(b0 + (tid >> 1)) * 256 + t * 2 + (tid & 1)];
    }
    __syncthreads();
    {  // e(t) -> eh[..][0]
      const int k = j;
      float a0 = A0[t * 128 + k], a1 = A1[t * 128 + k], cc = C[t * 128 + k];
#pragma unroll
      for (int s = 0; s < 16; ++s) {
        int sb = sbg * 16 + s;
        float e = xs[sb][0] * a0 + xs[sb][1] * a1 + cc;
        eh[sb][k][0] = fmaxf(e, 0.f);
      }
    }
    __syncthreads();
    // gates: acc[s] = bias + sum_k e*w_ih + h*w_hh
    float ai[16], af[16], ag[16], ao[16];
#pragma unroll
    for (int s = 0; s < 16; ++s) { ai[s] = bi; af[s] = bf; ag[s] = bg; ao[s] = bo; }
#pragma unroll 2
    for (int k = 0; k < 128; ++k) {
      const float* wk = wT + k * 1024;
      float wi0 = wk[j], wi1 = wk[128 + j], wi2 = wk[256 + j], wi3 = wk[384 + j];
      float wh0 = wk[512 + j], wh1 = wk[640 + j], wh2 = wk[768 + j], wh3 = wk[896 + j];
#pragma unroll
      for (int s = 0; s < 16; ++s) {
        int sb = sbg * 16 + s;
        float e = eh[sb][k][0];  // wave-uniform broadcast
        float h = eh[sb][k][1];
        ai[s] += e * wi0 + h * wh0;
        af[s] += e * wi1 + h * wh1;
        ag[s] += e * wi2 + h * wh2;
        ao[s] += e * wi3 + h * wh3;
      }
    }
    __syncthreads();  // all gate reads of eh done
#pragma unroll
    for (int s = 0; s < 16; ++s) {
      int sb = sbg * 16 + s;
      float ig = sigmoidf_(ai[s]);
      float fg = sigmoidf_(af[s]);
      float gg = tanhf_(ag[s]);
      float og = sigmoidf_(ao[s]);
      float cn = fg * c[s] + ig * gg;
      c[s] = cn;
      eh[sb][j][1] = og * tanhf_(cn);  // h_t
    }
    __syncthreads();
    // z = h @ w_out.T + b_out  (raw, pre-BN) -> d_out as scratch + block-partial stats
    if (tid < 160) {
      float acc = b_out[zo];
      const float* wo = w_out + zo * 128;
      for (int k = 0; k < 128; ++k) acc += eh[zsb][k][1] * wo[k];
      out[(b0 + zsb) * (T_ * OUT_) + t * OUT_ + zo] = acc;
      zs[zsb][zo] = acc;
    }
    __syncthreads();
    if (tid < 10) {
      int o = tid >> 1, kind = tid & 1;
      float a = 0.f;
      for (int sb = 0; sb < 32; ++sb) {
        float v = zs[sb][o];
        a += kind ? v * v : v;
      }
      atomicAdd(&zstats[t * 10 + o * 2 + kind], a);
    }
  }
}

// ---- kernel 5: in-place output BN + ReLU ----
__global__ void k_outbn(float* __restrict__ out, const float* __restrict__ zstats,
                        const float* __restrict__ gamma2, const float* __restrict__ beta2) {
  int idx = blockIdx.x * 256 + threadIdx.x;  // 0 .. B*T*5-1 (20,971,520)
  int r = idx % 640;                         // T*5
  int t = r / 5, o = r - t * 5;
  float z = out[idx];
  float sum = zstats[t * 10 + o * 2];
  float ss = zstats[t * 10 + o * 2 + 1];
  float mu = sum * (1.f / (float)B_);
  float var = ss * (1.f / (float)B_) - mu * mu;
  float y = gamma2[o] * (z - mu) * rsqrtf(var + EPS_) + beta2[o];
  out[idx] = fmaxf(y, 0.f);
}

extern "C" void kernel_launch(void* const* d_in, const int* in_sizes, int n_in, void* d_out,
                              int out_size, void* d_ws, size_t ws_size, hipStream_t stream) {
  const float* x = (const float*)d_in[0];
  const float* w_emb = (const float*)d_in[1];
  const float* b_emb = (const float*)d_in[2];
  const float* gamma1 = (const float*)d_in[3];
  const float* beta1 = (const float*)d_in[4];
  const float* w_ih = (const float*)d_in[5];
  const float* w_hh = (const float*)d_in[6];
  const float* b_ih = (const float*)d_in[7];
  const float* b_hh = (const float*)d_in[8];
  const float* w_out = (const float*)d_in[9];
  const float* b_out = (const float*)d_in[10];
  const float* gamma2 = (const float*)d_in[11];
  const float* beta2 = (const float*)d_in[12];
  float* out = (float*)d_out;
  float* ws = (float*)d_ws;

  float* wT = ws + WS_WT;
  float* istats = ws + WS_ISTATS;
  float* A0 = ws + WS_A0;
  float* A1 = ws + WS_A1;
  float* C = ws + WS_C;
  float* zst = ws + WS_ZST;

  hipMemsetAsync(istats, 0, 128 * 5 * sizeof(float), stream);
  hipMemsetAsync(zst, 0, 128 * 5 * 2 * sizeof(float), stream);

  k_istats<<<512, 256, 0, stream>>>(x, istats);
  k_prep_w<<<512, 256, 0, stream>>>(w_ih, w_hh, wT);
  k_coef<<<64, 256, 0, stream>>>(istats, w_emb, b_emb, gamma1, beta1, A0, A1, C);
  k_lstm<<<1024, 256, 0, stream>>>(x, wT, A0, A1, C, b_ih, b_hh, w_out, b_out, out, zst);
  k_outbn<<<(B_ * T_ * OUT_) / 256, 256, 0, stream>>>(out, zst, gamma2, beta2);
}

// Round 2
// 3271.600 us; speedup vs baseline: 7.1463x; 7.1463x over previous
//
#include <hip/hip_runtime.h>
#include <math.h>

#define B_    32768
#define T_    128
#define OUT_  5
#define EPS_  1e-5f

typedef float f32x4 __attribute__((ext_vector_type(4)));
typedef __bf16 bfrag __attribute__((ext_vector_type(8)));
typedef unsigned short ushort_t;

// ---- workspace layout (float offsets) ----
// Wc:    ushort [528][256]  = 135168 ushort = 67584 floats  (gate weight rows g: [w_ih | w_hh];
//                             rows 512..516: [0 | w_out]; 517..527: 0)
// gbias: [528]   b_ih+b_hh (g<512), b_out (512..516), 0
// A0/A1/C: [128][128] folded embed+BN coeffs
// istats: [128][5], zstats: [128][5][2]
#define WS_WC   0
#define WS_GB   67584
#define WS_A0   68112
#define WS_A1   84496
#define WS_C    100880
#define WS_IST  117264
#define WS_ZST  117904

__device__ __forceinline__ ushort_t f2bf(float f) {  // RNE
  unsigned u = __float_as_uint(f);
  u += 0x7FFFu + ((u >> 16) & 1u);
  return (ushort_t)(u >> 16);
}
__device__ __forceinline__ float fsig(float x) {
  return __builtin_amdgcn_rcpf(1.f + __expf(-x));
}
__device__ __forceinline__ float ftanh(float x) {
  return 1.f - 2.f * __builtin_amdgcn_rcpf(1.f + __expf(2.f * x));
}

// ---- kernel 1: per-timestep input moments (unchanged from R1, verified) ----
__global__ void k_istats(const float* __restrict__ x, float* __restrict__ istats) {
  const int tid = threadIdx.x;
  const int t = tid >> 1;
  const int i = tid & 1;
  const long b0 = (long)blockIdx.x * 64;
  float s_v = 0.f, s_vv = 0.f, s_cross = 0.f;
  for (int s = 0; s < 64; ++s) {
    float v = x[(b0 + s) * 256 + tid];
    float p = __shfl_xor(v, 1);
    s_v += v; s_vv += v * v; s_cross += v * p;
  }
  float* st = istats + t * 5;
  if (i == 0) {
    atomicAdd(st + 0, s_v); atomicAdd(st + 2, s_vv); atomicAdd(st + 4, s_cross);
  } else {
    atomicAdd(st + 1, s_v); atomicAdd(st + 3, s_vv);
  }
}

// ---- kernel 2: pack weights to bf16 Wc[528][256] + gbias ----
__global__ void k_prep_w(const float* __restrict__ w_ih, const float* __restrict__ w_hh,
                         const float* __restrict__ w_out, const float* __restrict__ b_ih,
                         const float* __restrict__ b_hh, const float* __restrict__ b_out,
                         ushort_t* __restrict__ Wc, float* __restrict__ gbias) {
  int idx = blockIdx.x * 256 + threadIdx.x;  // 0 .. 135167
  int g = idx >> 8, k = idx & 255;
  float v;
  if (g < 512)      v = (k < 128) ? w_ih[g * 128 + k] : w_hh[g * 128 + (k - 128)];
  else if (g < 517) v = (k < 128) ? 0.f : w_out[(g - 512) * 128 + (k - 128)];
  else              v = 0.f;
  Wc[idx] = f2bf(v);
  if (idx < 528) {
    float bv = (idx < 512) ? b_ih[idx] + b_hh[idx]
                           : (idx < 517 ? b_out[idx - 512] : 0.f);
    gbias[idx] = bv;
  }
}

// ---- kernel 3: fold embed linear + BN into per-(t,f) affine coeffs (unchanged) ----
__global__ void k_coef(const float* __restrict__ istats, const float* __restrict__ w_emb,
                       const float* __restrict__ b_emb, const float* __restrict__ gamma1,
                       const float* __restrict__ beta1, float* __restrict__ A0,
                       float* __restrict__ A1, float* __restrict__ C) {
  int idx = blockIdx.x * 256 + threadIdx.x;  // 0 .. 16383
  int t = idx >> 7, f = idx & 127;
  const float* st = istats + t * 5;
  const float invB = 1.f / (float)B_;
  float m0 = st[0] * invB, m1 = st[1] * invB;
  float v00 = st[2] * invB - m0 * m0;
  float v11 = st[3] * invB - m1 * m1;
  float c01 = st[4] * invB - m0 * m1;
  float w0 = w_emb[f * 2 + 0], w1 = w_emb[f * 2 + 1];
  float mu = m0 * w0 + m1 * w1 + b_emb[f];
  float var = w0 * w0 * v00 + w1 * w1 * v11 + 2.f * w0 * w1 * c01;
  float alpha = gamma1[f] * rsqrtf(var + EPS_);
  A0[t * 128 + f] = alpha * w0;
  A1[t * 128 + f] = alpha * w1;
  C[t * 128 + f] = alpha * (b_emb[f] - mu) + beta1[f];
}

// ---- kernel 4: MFMA recurrent LSTM ----
// 256 blocks x 512 threads (8 waves), S=128 samples/block, 1 block/CU.
// Per t: stage e(t) (bf16) into Abuf cols [0,128); Abuf cols [128,256) hold h(t-1).
// MFMA: gates[128][512] = Abuf @ Wc^T tiles; wave w owns n-tiles {w,w+8,w+16,w+24}
// == gates i,f,g,o of cells j in [16w,16w+16)  -> elementwise is register-local.
// z(t-1) = h(t-1) @ w_out^T via tile 32 (ks>=4 only), wave w does its own m-tile.
__global__ __launch_bounds__(512, 2) void k_lstm(
    const float* __restrict__ x, const ushort_t* __restrict__ Wc,
    const float* __restrict__ gbias, const float* __restrict__ A0,
    const float* __restrict__ A1, const float* __restrict__ Cc,
    float* __restrict__ out, float* __restrict__ zstats) {
  __shared__ __align__(16) ushort_t Abuf[128][272];  // 69.6 KB, row stride 544B
  __shared__ float zred[8][5], zred2[8][5];

  const int tid = threadIdx.x;
  const int w = tid >> 6;        // wave 0..7
  const int l = tid & 63;
  const int lm = l & 15;         // MFMA lane col
  const int lq = l >> 4;         // MFMA quad
  const long b0 = (long)blockIdx.x * 128;

  // zero Abuf (h(-1)=0; rest hygiene)
  for (int i = tid; i < 128 * 272 / 8; i += 512)
    ((uint4*)&Abuf[0][0])[i] = make_uint4(0u, 0u, 0u, 0u);

  // per-lane constants
  float bias_g[4];
#pragma unroll
  for (int i = 0; i < 4; ++i) bias_g[i] = gbias[(w + 8 * i) * 16 + lm];
  const float bias_z = gbias[512 + lm];

  const uint4* wptr[4];
#pragma unroll
  for (int i = 0; i < 4; ++i)
    wptr[i] = (const uint4*)(Wc + (size_t)((w + 8 * i) * 16 + lm) * 256 + lq * 8);
  const uint4* wzptr = (const uint4*)(Wc + (size_t)(512 + lm) * 256 + lq * 8);

  // e-staging roles: row em, 16B chunk ec (4 phases cover cols 0..127)
  const int em = (w << 4) + (l >> 2);
  const int ec = l & 3;
  const float2* x2 = (const float2*)x;

  float cst[8][4];
#pragma unroll
  for (int mt = 0; mt < 8; ++mt)
#pragma unroll
    for (int r = 0; r < 4; ++r) cst[mt][r] = 0.f;

  __syncthreads();  // Abuf zero visible

  for (int t = 0; t <= T_; ++t) {
    // ---- stage e(t) ----
    if (t < T_) {
      float2 xv = x2[(size_t)(b0 + em) * 128 + t];
#pragma unroll
      for (int p = 0; p < 4; ++p) {
        const int f0 = p * 32 + ec * 8;
        const f32x4 a0l = *(const f32x4*)(A0 + t * 128 + f0);
        const f32x4 a0h = *(const f32x4*)(A0 + t * 128 + f0 + 4);
        const f32x4 a1l = *(const f32x4*)(A1 + t * 128 + f0);
        const f32x4 a1h = *(const f32x4*)(A1 + t * 128 + f0 + 4);
        const f32x4 ccl = *(const f32x4*)(Cc + t * 128 + f0);
        const f32x4 cch = *(const f32x4*)(Cc + t * 128 + f0 + 4);
        unsigned pk[4];
#pragma unroll
        for (int h2 = 0; h2 < 4; ++h2) {
          float e0, e1;
          if (h2 < 2) {
            e0 = fmaf(xv.x, a0l[h2 * 2], fmaf(xv.y, a1l[h2 * 2], ccl[h2 * 2]));
            e1 = fmaf(xv.x, a0l[h2 * 2 + 1], fmaf(xv.y, a1l[h2 * 2 + 1], ccl[h2 * 2 + 1]));
          } else {
            e0 = fmaf(xv.x, a0h[(h2 - 2) * 2], fmaf(xv.y, a1h[(h2 - 2) * 2], cch[(h2 - 2) * 2]));
            e1 = fmaf(xv.x, a0h[(h2 - 2) * 2 + 1],
                      fmaf(xv.y, a1h[(h2 - 2) * 2 + 1], cch[(h2 - 2) * 2 + 1]));
          }
          e0 = fmaxf(e0, 0.f); e1 = fmaxf(e1, 0.f);
          pk[h2] = (unsigned)f2bf(e0) | ((unsigned)f2bf(e1) << 16);
        }
        *(uint4*)&Abuf[em][f0] = make_uint4(pk[0], pk[1], pk[2], pk[3]);
      }
    }
    __syncthreads();  // B1: e(t) + h(t-1) ready

    // ---- MFMA pass ----
    f32x4 acc[8][4];
#pragma unroll
    for (int mt = 0; mt < 8; ++mt)
#pragma unroll
      for (int i = 0; i < 4; ++i) {
        f32x4 v = {bias_g[i], bias_g[i], bias_g[i], bias_g[i]};
        acc[mt][i] = v;
      }
    f32x4 zac = {bias_z, bias_z, bias_z, bias_z};

#pragma unroll
    for (int ks = 0; ks < 8; ++ks) {
      bfrag Bf[4];
#pragma unroll
      for (int i = 0; i < 4; ++i)
        Bf[i] = __builtin_bit_cast(bfrag, wptr[i][ks * 4]);
      bfrag Bz;
      if (ks >= 4) Bz = __builtin_bit_cast(bfrag, wzptr[ks * 4]);
#pragma unroll
      for (int mt = 0; mt < 8; ++mt) {
        bfrag Af = __builtin_bit_cast(bfrag, *(const uint4*)&Abuf[mt * 16 + lm][ks * 32 + lq * 8]);
#pragma unroll
        for (int i = 0; i < 4; ++i)
          acc[mt][i] = __builtin_amdgcn_mfma_f32_16x16x32_bf16(Af, Bf[i], acc[mt][i], 0, 0, 0);
        if (ks >= 4 && mt == w)
          zac = __builtin_amdgcn_mfma_f32_16x16x32_bf16(Af, Bz, zac, 0, 0, 0);
      }
    }

    // ---- z(t-1): store raw + wave-partial stats ----
    if (t > 0) {
      float sz = 0.f, sq = 0.f;
#pragma unroll
      for (int r = 0; r < 4; ++r) {
        float zv = zac[r];
        if (lm < OUT_)
          out[(size_t)(b0 + (w << 4) + lq * 4 + r) * (T_ * OUT_) + (size_t)(t - 1) * OUT_ + lm] = zv;
        sz += zv; sq += zv * zv;
      }
      sz += __shfl_xor(sz, 16); sz += __shfl_xor(sz, 32);
      sq += __shfl_xor(sq, 16); sq += __shfl_xor(sq, 32);
      if (lq == 0 && lm < OUT_) { zred[w][lm] = sz; zred2[w][lm] = sq; }
    }
    __syncthreads();  // B2: MFMA reads of Abuf done; zred ready

    if (t > 0 && tid < 10) {
      int o = tid >> 1, kind = tid & 1;
      float s = 0.f;
#pragma unroll
      for (int ww = 0; ww < 8; ++ww) s += kind ? zred2[ww][o] : zred[ww][o];
      atomicAdd(&zstats[(size_t)(t - 1) * 10 + o * 2 + kind], s);
    }

    // ---- elementwise LSTM: register-local gates -> h(t) into Abuf ----
    if (t < T_) {
#pragma unroll
      for (int mt = 0; mt < 8; ++mt) {
#pragma unroll
        for (int r = 0; r < 4; ++r) {
          float gi = acc[mt][0][r], gf = acc[mt][1][r];
          float gg = acc[mt][2][r], go = acc[mt][3][r];
          float ig = fsig(gi), fg = fsig(gf), g2 = ftanh(gg), og = fsig(go);
          float cn = fmaf(fg, cst[mt][r], ig * g2);
          cst[mt][r] = cn;
          float h = og * ftanh(cn);
          Abuf[mt * 16 + lq * 4 + r][128 + (w << 4) + lm] = f2bf(h);
        }
      }
    }
    // h-writes ordered before next MFMA reads by B1 of the next iteration.
  }
}

// ---- kernel 5: in-place output BN + ReLU (unchanged) ----
__global__ void k_outbn(float* __restrict__ out, const float* __restrict__ zstats,
                        const float* __restrict__ gamma2, const float* __restrict__ beta2) {
  int idx = blockIdx.x * 256 + threadIdx.x;
  int r = idx % 640;
  int t = r / 5, o = r - t * 5;
  float z = out[idx];
  float sum = zstats[t * 10 + o * 2];
  float ss = zstats[t * 10 + o * 2 + 1];
  float mu = sum * (1.f / (float)B_);
  float var = ss * (1.f / (float)B_) - mu * mu;
  float y = gamma2[o] * (z - mu) * rsqrtf(var + EPS_) + beta2[o];
  out[idx] = fmaxf(y, 0.f);
}

extern "C" void kernel_launch(void* const* d_in, const int* in_sizes, int n_in, void* d_out,
                              int out_size, void* d_ws, size_t ws_size, hipStream_t stream) {
  const float* x = (const float*)d_in[0];
  const float* w_emb = (const float*)d_in[1];
  const float* b_emb = (const float*)d_in[2];
  const float* gamma1 = (const float*)d_in[3];
  const float* beta1 = (const float*)d_in[4];
  const float* w_ih = (const float*)d_in[5];
  const float* w_hh = (const float*)d_in[6];
  const float* b_ih = (const float*)d_in[7];
  const float* b_hh = (const float*)d_in[8];
  const float* w_out = (const float*)d_in[9];
  const float* b_out = (const float*)d_in[10];
  const float* gamma2 = (const float*)d_in[11];
  const float* beta2 = (const float*)d_in[12];
  float* out = (float*)d_out;
  float* ws = (float*)d_ws;

  ushort_t* Wc = (ushort_t*)(ws + WS_WC);
  float* gbias = ws + WS_GB;
  float* A0 = ws + WS_A0;
  float* A1 = ws + WS_A1;
  float* C = ws + WS_C;
  float* istats = ws + WS_IST;
  float* zstats = ws + WS_ZST;

  hipMemsetAsync(istats, 0, 640 * sizeof(float), stream);
  hipMemsetAsync(zstats, 0, 1280 * sizeof(float), stream);

  k_istats<<<512, 256, 0, stream>>>(x, istats);
  k_prep_w<<<528, 256, 0, stream>>>(w_ih, w_hh, w_out, b_ih, b_hh, b_out, Wc, gbias);
  k_coef<<<64, 256, 0, stream>>>(istats, w_emb, b_emb, gamma1, beta1, A0, A1, C);
  k_lstm<<<256, 512, 0, stream>>>(x, Wc, gbias, A0, A1, C, out, zstats);
  k_outbn<<<(B_ * T_ * OUT_) / 256, 256, 0, stream>>>(out, zstats, gamma2, beta2);
}

// Round 5
// 2795.650 us; speedup vs baseline: 8.3629x; 1.1702x over previous
//
#include <hip/hip_runtime.h>
#include <math.h>

#define B_    32768
#define T_    128
#define OUT_  5
#define EPS_  1e-5f

typedef float f32x4 __attribute__((ext_vector_type(4)));
typedef __bf16 bfrag __attribute__((ext_vector_type(8)));
typedef unsigned short ushort_t;

// ---- workspace layout (float offsets) — EXACTLY R2's proven 119184-float footprint ----
// Wc2:   ushort[33][8][4][16][8] = 135168 ushorts = 67584 floats (fragment-ordered:
//        tile T<32: rows g=16T+lm (g=gate*128+cell); T=32: z/w_out rows; k=ks*32+lq*8+e)
// gbias: [528]  b_ih+b_hh (g<512), b_out (512..516), 0
// A0/A1/C: [128][128] folded embed+BN coefficients
// istats:[128][5], zstats:[128][5][2]
#define WS_WC2   0
#define WS_GB    67584
#define WS_A0    68112
#define WS_A1    84496
#define WS_C     100880
#define WS_IST   117264
#define WS_ZST   117904

__device__ __forceinline__ ushort_t f2bf(float f) {  // RNE
  unsigned u = __float_as_uint(f);
  u += 0x7FFFu + ((u >> 16) & 1u);
  return (ushort_t)(u >> 16);
}
__device__ __forceinline__ float fsig(float x) {
  return __builtin_amdgcn_rcpf(1.f + __expf(-x));
}
__device__ __forceinline__ float ftanh(float x) {
  return 1.f - 2.f * __builtin_amdgcn_rcpf(1.f + __expf(2.f * x));
}

// ---- kernel 1: per-timestep input moments (verified) ----
__global__ void k_istats(const float* __restrict__ x, float* __restrict__ istats) {
  const int tid = threadIdx.x;
  const int t = tid >> 1;
  const int i = tid & 1;
  const long b0 = (long)blockIdx.x * 64;
  float s_v = 0.f, s_vv = 0.f, s_cross = 0.f;
  for (int s = 0; s < 64; ++s) {
    float v = x[(b0 + s) * 256 + tid];
    float p = __shfl_xor(v, 1);
    s_v += v; s_vv += v * v; s_cross += v * p;
  }
  float* st = istats + t * 5;
  if (i == 0) {
    atomicAdd(st + 0, s_v); atomicAdd(st + 2, s_vv); atomicAdd(st + 4, s_cross);
  } else {
    atomicAdd(st + 1, s_v); atomicAdd(st + 3, s_vv);
  }
}

// ---- kernel 2: pack weights to fragment-ordered bf16 Wc2 + gbias ----
__global__ void k_prep_w(const float* __restrict__ w_ih, const float* __restrict__ w_hh,
                         const float* __restrict__ w_out, const float* __restrict__ b_ih,
                         const float* __restrict__ b_hh, const float* __restrict__ b_out,
                         ushort_t* __restrict__ Wc2, float* __restrict__ gbias) {
  int idx = blockIdx.x * 256 + threadIdx.x;  // 0 .. 135167
  int e = idx & 7;
  int lm = (idx >> 3) & 15;
  int lq = (idx >> 7) & 3;
  int ks = (idx >> 9) & 7;
  int T = idx >> 12;
  int k = ks * 32 + lq * 8 + e;
  float v;
  if (T < 32) {
    int g = T * 16 + lm;  // row = gate*128 + cell
    v = (k < 128) ? w_ih[g * 128 + k] : w_hh[g * 128 + (k - 128)];
  } else {
    v = (k >= 128 && lm < OUT_) ? w_out[lm * 128 + (k - 128)] : 0.f;
  }
  Wc2[idx] = f2bf(v);
  if (idx < 528) {
    float bv = (idx < 512) ? b_ih[idx] + b_hh[idx]
                           : (idx < 517 ? b_out[idx - 512] : 0.f);
    gbias[idx] = bv;
  }
}

// ---- kernel 3: fold embed linear + BN into per-(t,f) affine coeffs (R2-verified) ----
__global__ void k_coef(const float* __restrict__ istats, const float* __restrict__ w_emb,
                       const float* __restrict__ b_emb, const float* __restrict__ gamma1,
                       const float* __restrict__ beta1, float* __restrict__ A0,
                       float* __restrict__ A1, float* __restrict__ C) {
  int idx = blockIdx.x * 256 + threadIdx.x;  // 0 .. 16383
  int t = idx >> 7, f = idx & 127;
  const float* st = istats + t * 5;
  const float invB = 1.f / (float)B_;
  float m0 = st[0] * invB, m1 = st[1] * invB;
  float v00 = st[2] * invB - m0 * m0;
  float v11 = st[3] * invB - m1 * m1;
  float c01 = st[4] * invB - m0 * m1;
  float w0 = w_emb[f * 2 + 0], w1 = w_emb[f * 2 + 1];
  float mu = m0 * w0 + m1 * w1 + b_emb[f];
  float var = w0 * w0 * v00 + w1 * w1 * v11 + 2.f * w0 * w1 * c01;
  float alpha = gamma1[f] * rsqrtf(var + EPS_);
  A0[t * 128 + f] = alpha * w0;
  A1[t * 128 + f] = alpha * w1;
  C[t * 128 + f] = alpha * (b_emb[f] - mu) + beta1[f];
}

// ---- kernel 4: MFMA recurrent LSTM ----
// 256 blocks x 512 threads (8 waves), S=128 samples/block.
// Wave w owns gate tiles {w,w+8,w+16,w+24} = gates i,f,g,o of cells [16w,16w+16):
// elementwise is register-local. Weights: global->VGPR in fragment order,
// register double-buffer (depth-1 prefetch), per-block ks-phase rotation to
// desynchronize the 32 blocks/XCD on the shared 264 KB weight stream.
__global__ __launch_bounds__(512, 2) void k_lstm(
    const float* __restrict__ x, const ushort_t* __restrict__ Wc2,
    const float* __restrict__ gbias, const float* __restrict__ A0,
    const float* __restrict__ A1, const float* __restrict__ Cc,
    float* __restrict__ out, float* __restrict__ zstats) {
  __shared__ __align__(16) ushort_t Abuf[128][272];  // 69.6 KB
  __shared__ float zred[8][5], zred2[8][5];

  const int tid = threadIdx.x;
  const int w = tid >> 6;   // wave 0..7
  const int l = tid & 63;
  const int lm = l & 15;    // MFMA lane col
  const int lq = l >> 4;    // MFMA quad
  const long b0 = (long)blockIdx.x * 128;
  const int phase = blockIdx.x & 7;  // ks-rotation phase (desync L2 bursts)

  const uint4* W4 = (const uint4*)Wc2;  // frag(T,ks,lane) = W4[(T*8+ks)*64 + lane]
  int tb[4];
#pragma unroll
  for (int i = 0; i < 4; ++i) tb[i] = (w + 8 * i) * 8 * 64;

  // zero Abuf (h(-1)=0)
  for (int i = tid; i < 128 * 272 / 8; i += 512)
    ((uint4*)&Abuf[0][0])[i] = make_uint4(0u, 0u, 0u, 0u);

  float bias_g[4];
#pragma unroll
  for (int i = 0; i < 4; ++i) bias_g[i] = gbias[(w + 8 * i) * 16 + lm];
  const float bias_z = gbias[512 + lm];

  // e-staging roles: row em, 16B chunk ec
  const int em = (w << 4) + (l >> 2);
  const int ec = l & 3;
  const float2* x2 = (const float2*)x;

  float cst[8][4];
#pragma unroll
  for (int mt = 0; mt < 8; ++mt)
#pragma unroll
    for (int r = 0; r < 4; ++r) cst[mt][r] = 0.f;

  // preload first weight chunk (chunk index = phase) into buffer 0
  uint4 wb[2][4];
#pragma unroll
  for (int i = 0; i < 4; ++i) wb[0][i] = W4[tb[i] + phase * 64 + l];

  __syncthreads();  // Abuf zero visible

  for (int t = 0; t <= T_; ++t) {
    // ---- stage e(t) ----
    if (t < T_) {
      float2 xv = x2[(size_t)(b0 + em) * 128 + t];
#pragma unroll
      for (int p = 0; p < 4; ++p) {
        const int f0 = p * 32 + ec * 8;
        const f32x4 a0l = *(const f32x4*)(A0 + t * 128 + f0);
        const f32x4 a0h = *(const f32x4*)(A0 + t * 128 + f0 + 4);
        const f32x4 a1l = *(const f32x4*)(A1 + t * 128 + f0);
        const f32x4 a1h = *(const f32x4*)(A1 + t * 128 + f0 + 4);
        const f32x4 ccl = *(const f32x4*)(Cc + t * 128 + f0);
        const f32x4 cch = *(const f32x4*)(Cc + t * 128 + f0 + 4);
        unsigned pk[4];
#pragma unroll
        for (int h2 = 0; h2 < 4; ++h2) {
          float e0, e1;
          if (h2 < 2) {
            e0 = fmaf(xv.x, a0l[h2 * 2], fmaf(xv.y, a1l[h2 * 2], ccl[h2 * 2]));
            e1 = fmaf(xv.x, a0l[h2 * 2 + 1], fmaf(xv.y, a1l[h2 * 2 + 1], ccl[h2 * 2 + 1]));
          } else {
            e0 = fmaf(xv.x, a0h[(h2 - 2) * 2], fmaf(xv.y, a1h[(h2 - 2) * 2], cch[(h2 - 2) * 2]));
            e1 = fmaf(xv.x, a0h[(h2 - 2) * 2 + 1],
                      fmaf(xv.y, a1h[(h2 - 2) * 2 + 1], cch[(h2 - 2) * 2 + 1]));
          }
          e0 = fmaxf(e0, 0.f); e1 = fmaxf(e1, 0.f);
          pk[h2] = (unsigned)f2bf(e0) | ((unsigned)f2bf(e1) << 16);
        }
        *(uint4*)&Abuf[em][f0] = make_uint4(pk[0], pk[1], pk[2], pk[3]);
      }
    }
    __syncthreads();  // B1: e(t) + h(t-1) ready

    // ---- MFMA gate pass: 8 k-chunks, rotated start, reg double-buffer ----
    f32x4 acc[8][4];
#pragma unroll
    for (int mt = 0; mt < 8; ++mt)
#pragma unroll
      for (int i = 0; i < 4; ++i) {
        f32x4 v = {bias_g[i], bias_g[i], bias_g[i], bias_g[i]};
        acc[mt][i] = v;
      }

    int ks = phase;
#pragma unroll
    for (int kk = 0; kk < 8; ++kk) {
      const int p = kk & 1;
      const int ksn = (ks + 1) & 7;
      // prefetch next chunk (at kk=7 this reloads chunk `phase` for the next t)
#pragma unroll
      for (int i = 0; i < 4; ++i) wb[p ^ 1][i] = W4[tb[i] + ksn * 64 + l];
      bfrag Bf[4];
#pragma unroll
      for (int i = 0; i < 4; ++i) Bf[i] = __builtin_bit_cast(bfrag, wb[p][i]);
#pragma unroll
      for (int mt = 0; mt < 8; ++mt) {
        bfrag Af = __builtin_bit_cast(bfrag, *(const uint4*)&Abuf[mt * 16 + lm][ks * 32 + lq * 8]);
#pragma unroll
        for (int i = 0; i < 4; ++i)
          acc[mt][i] = __builtin_amdgcn_mfma_f32_16x16x32_bf16(Af, Bf[i], acc[mt][i], 0, 0, 0);
      }
      ks = ksn;
    }

    // ---- z(t-1) = h(t-1) @ w_out^T: static chunks 4..7, wave's own m-tile ----
    f32x4 zac = {bias_z, bias_z, bias_z, bias_z};
#pragma unroll
    for (int i = 0; i < 4; ++i) {
      uint4 wz = W4[(32 * 8 + 4 + i) * 64 + l];
      bfrag Af = __builtin_bit_cast(bfrag, *(const uint4*)&Abuf[w * 16 + lm][(4 + i) * 32 + lq * 8]);
      zac = __builtin_amdgcn_mfma_f32_16x16x32_bf16(Af, __builtin_bit_cast(bfrag, wz), zac, 0, 0, 0);
    }

    // ---- z(t-1): store raw + wave-partial stats ----
    if (t > 0) {
      float sz = 0.f, sq = 0.f;
#pragma unroll
      for (int r = 0; r < 4; ++r) {
        float zv = zac[r];
        if (lm < OUT_)
          out[(size_t)(b0 + (w << 4) + lq * 4 + r) * (T_ * OUT_) + (size_t)(t - 1) * OUT_ + lm] = zv;
        sz += zv; sq += zv * zv;
      }
      sz += __shfl_xor(sz, 16); sz += __shfl_xor(sz, 32);
      sq += __shfl_xor(sq, 16); sq += __shfl_xor(sq, 32);
      if (lq == 0 && lm < OUT_) { zred[w][lm] = sz; zred2[w][lm] = sq; }
    }
    __syncthreads();  // B2: Abuf reads done; zred ready

    if (t > 0 && tid < 10) {
      int o = tid >> 1, kind = tid & 1;
      float s = 0.f;
#pragma unroll
      for (int ww = 0; ww < 8; ++ww) s += kind ? zred2[ww][o] : zred[ww][o];
      atomicAdd(&zstats[(size_t)(t - 1) * 10 + o * 2 + kind], s);
    }

    // ---- elementwise LSTM: register-local gates -> h(t) into Abuf ----
    if (t < T_) {
#pragma unroll
      for (int mt = 0; mt < 8; ++mt) {
#pragma unroll
        for (int r = 0; r < 4; ++r) {
          float gi = acc[mt][0][r], gf = acc[mt][1][r];
          float gg = acc[mt][2][r], go = acc[mt][3][r];
          float ig = fsig(gi), fg = fsig(gf), g2 = ftanh(gg), og = fsig(go);
          float cn = fmaf(fg, cst[mt][r], ig * g2);
          cst[mt][r] = cn;
          float h = og * ftanh(cn);
          Abuf[mt * 16 + lq * 4 + r][128 + (w << 4) + lm] = f2bf(h);
        }
      }
    }
  }
}

// ---- kernel 5: in-place output BN + ReLU (verified) ----
__global__ void k_outbn(float* __restrict__ out, const float* __restrict__ zstats,
                        const float* __restrict__ gamma2, const float* __restrict__ beta2) {
  int idx = blockIdx.x * 256 + threadIdx.x;
  int r = idx % 640;
  int t = r / 5, o = r - t * 5;
  float z = out[idx];
  float sum = zstats[t * 10 + o * 2];
  float ss = zstats[t * 10 + o * 2 + 1];
  float mu = sum * (1.f / (float)B_);
  float var = ss * (1.f / (float)B_) - mu * mu;
  float y = gamma2[o] * (z - mu) * rsqrtf(var + EPS_) + beta2[o];
  out[idx] = fmaxf(y, 0.f);
}

extern "C" void kernel_launch(void* const* d_in, const int* in_sizes, int n_in, void* d_out,
                              int out_size, void* d_ws, size_t ws_size, hipStream_t stream) {
  const float* x = (const float*)d_in[0];
  const float* w_emb = (const float*)d_in[1];
  const float* b_emb = (const float*)d_in[2];
  const float* gamma1 = (const float*)d_in[3];
  const float* beta1 = (const float*)d_in[4];
  const float* w_ih = (const float*)d_in[5];
  const float* w_hh = (const float*)d_in[6];
  const float* b_ih = (const float*)d_in[7];
  const float* b_hh = (const float*)d_in[8];
  const float* w_out = (const float*)d_in[9];
  const float* b_out = (const float*)d_in[10];
  const float* gamma2 = (const float*)d_in[11];
  const float* beta2 = (const float*)d_in[12];
  float* out = (float*)d_out;
  float* ws = (float*)d_ws;

  ushort_t* Wc2 = (ushort_t*)(ws + WS_WC2);
  float* gbias = ws + WS_GB;
  float* A0 = ws + WS_A0;
  float* A1 = ws + WS_A1;
  float* C = ws + WS_C;
  float* istats = ws + WS_IST;
  float* zstats = ws + WS_ZST;

  hipMemsetAsync(istats, 0, 640 * sizeof(float), stream);
  hipMemsetAsync(zstats, 0, 1280 * sizeof(float), stream);

  k_istats<<<512, 256, 0, stream>>>(x, istats);
  k_prep_w<<<528, 256, 0, stream>>>(w_ih, w_hh, w_out, b_ih, b_hh, b_out, Wc2, gbias);
  k_coef<<<64, 256, 0, stream>>>(istats, w_emb, b_emb, gamma1, beta1, A0, A1, C);
  k_lstm<<<256, 512, 0, stream>>>(x, Wc2, gbias, A0, A1, C, out, zstats);
  k_outbn<<<(B_ * T_ * OUT_) / 256, 256, 0, stream>>>(out, zstats, gamma2, beta2);
}